// Round 1
// baseline (737.794 us; speedup 1.0000x reference)
//
#include <hip/hip_runtime.h>
#include <math.h>

typedef __bf16 bf16;
typedef __bf16 bf16x8 __attribute__((ext_vector_type(8)));
typedef float f32x4 __attribute__((ext_vector_type(4)));
typedef unsigned int u32x4 __attribute__((ext_vector_type(4)));

// ---------------------------------------------------------------------------
// Kernel 0: rearrange W2 [cout][ci][tap] f32 -> [tap][cout][ci] bf16 (one-time)
// so conv blocks can stage it into LDS with a coalesced identity copy and
// B-fragments read 8 contiguous ci per lane (ds_read_b128, conflict-free).
// ---------------------------------------------------------------------------
__global__ void prep_w2(const float* __restrict__ W2, bf16* __restrict__ w2g) {
    int e = blockIdx.x * 256 + threadIdx.x;     // e = (tap*64 + cout)*32 + ci
    if (e >= 9 * 64 * 32) return;
    int ci   = e & 31;
    int rest = e >> 5;
    int cout = rest & 63;
    int tap  = rest >> 6;
    w2g[e] = (bf16)W2[cout * 288 + ci * 9 + tap];
}

// ---------------------------------------------------------------------------
// Kernel 1: fused conv1(masked,relu) + conv2(masked,relu, MFMA) + 2x2 maxpool.
// One block = one image * 4 pooled rows (rb 0..2: rows 4, rb 3: rows 12,13).
// h1 tile in LDS as [row10][col30][ci32] bf16 (ci fastest -> b128 A-frags).
// Conv2 = implicit GEMM, M = (site,quad) positions, N = 64 couts, K = 9taps*32ci.
// ---------------------------------------------------------------------------
__global__ __launch_bounds__(256, 2)
void conv_fused(const float* __restrict__ x, const float* __restrict__ W1,
                const float* __restrict__ b1, const bf16* __restrict__ w2g,
                const float* __restrict__ b2, bf16* __restrict__ pooled)
{
    __shared__ __attribute__((aligned(16))) bf16  h1s[10 * 30 * 32];
    __shared__ __attribute__((aligned(16))) bf16  w2s[9 * 64 * 32];
    __shared__ __attribute__((aligned(16))) float xs[12 * 32];

    const int t   = threadIdx.x;
    const int img = blockIdx.x >> 2;
    const int rb  = blockIdx.x & 3;
    const int pr0 = rb * 4;                 // first pooled row of this block

    const float* xi = x + img * 784;

    // stage x tile: xs[j][c] = x[2*pr0-2+j][c-1] (zeros outside)
    for (int e = t; e < 12 * 32; e += 256) {
        int j  = e >> 5;
        int c  = e & 31;
        int xr = 2 * pr0 - 2 + j;
        int xc = c - 1;
        float v = 0.f;
        if (xr >= 0 && xr < 28 && xc >= 0 && xc < 28) v = xi[xr * 28 + xc];
        xs[e] = v;
    }
    // zero h1 tile (halo rows/cols must be 0)
    {
        unsigned int* hz = (unsigned int*)h1s;
        for (int e = t; e < (10 * 30 * 32) / 2; e += 256) hz[e] = 0u;
    }
    // stage rearranged W2 (identity copy, coalesced)
    {
        const u32x4* src = (const u32x4*)w2g;
        u32x4* dst = (u32x4*)w2s;
        for (int e = t; e < 2304; e += 256) dst[e] = src[e];
    }
    __syncthreads();

    // ---- conv1 (f32 VALU, small): thread = (ci = t&31, position group t>>5)
    {
        int ci = t & 31;
        int g  = t >> 5;
        float w[9];
        #pragma unroll
        for (int k = 0; k < 9; k++) w[k] = W1[ci * 9 + k];
        float bias = b1[ci];
        for (int p = g; p < 280; p += 8) {          // 10 rows x 28 cols
            int r  = p / 28;
            int xc = p - r * 28;
            int ghr = 2 * pr0 - 1 + r;              // global h1 row
            if (ghr >= 0 && ghr <= 27) {
                float s = bias;
                #pragma unroll
                for (int ky = 0; ky < 3; ky++)
                    #pragma unroll
                    for (int kx = 0; kx < 3; kx++)
                        s += xs[(r + ky) * 32 + xc + kx] * w[ky * 3 + kx];
                float cm = xs[(r + 1) * 32 + xc + 1];      // active-site mask
                float o  = (cm != 0.f && s > 0.f) ? s : 0.f;
                h1s[(r * 30 + xc + 1) * 32 + ci] = (bf16)o;
            }
        }
    }
    __syncthreads();

    // ---- conv2 via MFMA 16x16x32 bf16
    const int lane = t & 63;
    const int wv   = t >> 6;
    const int ml   = lane & 15;
    const int kg   = lane >> 4;
    const int nMt  = (rb < 3) ? 14 : 7;     // M-tiles of 16 positions

    f32x4 acc[4][4];
    {
        f32x4 z = {0.f, 0.f, 0.f, 0.f};
        #pragma unroll
        for (int i = 0; i < 4; i++)
            #pragma unroll
            for (int j = 0; j < 4; j++) acc[i][j] = z;
    }

    int pbase[4];
    int nMy = 0;
    #pragma unroll
    for (int i = 0; i < 4; i++) {
        int Mt = wv + 4 * i;
        if (Mt < nMt) {
            int m    = Mt * 16 + ml;        // A-frag row = lane&15
            int site = m >> 2;
            int q    = m & 3;
            int pi   = site / 14;
            int pj   = site - pi * 14;
            int y    = 2 * pi + (q >> 1);   // block-local conv2 row 0..7
            int xx   = 2 * pj + (q & 1);    // conv2 col 0..27
            pbase[i] = (y * 30 + xx) * 32 + kg * 8;
            nMy = i + 1;
        }
    }

    #pragma unroll
    for (int kt = 0; kt < 9; kt++) {        // tap = ky*3+kx, K-slice of 32 ci
        const int ky = kt / 3, kx = kt % 3;
        bf16x8 bfr[4];
        #pragma unroll
        for (int nt = 0; nt < 4; nt++)
            bfr[nt] = *(const bf16x8*)&w2s[(kt * 64 + nt * 16 + ml) * 32 + kg * 8];
        const int off = (ky * 30 + kx) * 32;
        #pragma unroll
        for (int i = 0; i < 4; i++) {
            if (i < nMy) {
                bf16x8 a = *(const bf16x8*)&h1s[pbase[i] + off];
                #pragma unroll
                for (int nt = 0; nt < 4; nt++)
                    acc[i][nt] = __builtin_amdgcn_mfma_f32_16x16x32_bf16(
                        a, bfr[nt], acc[i][nt], 0, 0, 0);
            }
        }
    }
    __syncthreads();    // all waves done reading h1s -> safe to overlay

    // ---- epilogue: +bias, mask, relu, 2x2 maxpool (quad lives in lane regs)
    bf16* pool_s = h1s;     // overlay: [cout][56 sites] bf16
    {
        float bias[4];
        #pragma unroll
        for (int nt = 0; nt < 4; nt++) bias[nt] = b2[nt * 16 + ml];
        #pragma unroll
        for (int i = 0; i < 4; i++) {
            if (i < nMy) {
                int Mt   = wv + 4 * i;
                int site = Mt * 4 + kg;     // (m = Mt*16 + kg*4 + r) >> 2
                int pi   = site / 14;
                int pj   = site - pi * 14;
                #pragma unroll
                for (int nt = 0; nt < 4; nt++) {
                    int cout = nt * 16 + ml;    // C/D col = lane&15
                    float pmax = 0.f;
                    #pragma unroll
                    for (int r = 0; r < 4; r++) {
                        float v  = acc[i][nt][r] + bias[nt];
                        int y    = 2 * pi + (r >> 1);
                        int xx   = 2 * pj + (r & 1);
                        float cm = xs[(y + 2) * 32 + xx + 1];
                        v = (cm != 0.f && v > 0.f) ? v : 0.f;
                        pmax = v > pmax ? v : pmax;
                    }
                    pool_s[cout * 56 + site] = (bf16)pmax;
                }
            }
        }
    }
    __syncthreads();

    // coalesced write-out: pooled[img][cout*196 + rb*56 + site] bf16 (as dwords)
    {
        const int nS   = (rb < 3) ? 56 : 28;
        const int half = nS >> 1;
        const unsigned int* ps = (const unsigned int*)pool_s;
        unsigned int* op = (unsigned int*)pooled;
        const int total = 64 * half;
        for (int e = t; e < total; e += 256) {
            int cout = e / half;
            int wd   = e - cout * half;
            op[img * 6272 + cout * 98 + rb * 28 + wd] = ps[cout * 28 + wd];
        }
    }
}

// ---------------------------------------------------------------------------
// Kernel 2: FC1 partial GEMM. C_part[ks] = A[m0:m0+64, ks*1568:(ks+1)*1568] * Wl1
// A = pooled bf16 [4096][12544]; Wl1 f32 [12544][128]. 512 blocks (64 M x 8 K).
// ---------------------------------------------------------------------------
__global__ __launch_bounds__(256)
void fc1(const bf16* __restrict__ pooled, const float* __restrict__ Wl1,
         float* __restrict__ part)
{
    __shared__ __attribute__((aligned(16))) float As[32][68];   // [k][m] padded
    __shared__ __attribute__((aligned(16))) float Bs[32][128];  // [k][n]

    const int t  = threadIdx.x;
    const int mb = blockIdx.x;
    const int ks = blockIdx.y;
    const int m0 = mb * 64;
    const int k0 = ks * 1568;
    const int tm = t >> 4;          // 0..15 -> 4 m rows
    const int tn = t & 15;          // 0..15 -> 8 n cols

    float acc[4][8];
    #pragma unroll
    for (int i = 0; i < 4; i++)
        #pragma unroll
        for (int j = 0; j < 8; j++) acc[i][j] = 0.f;

    const int am   = t >> 2;        // 0..63 (m row staged by this thread)
    const int kseg = (t & 3) * 8;   // 0,8,16,24

    for (int kt = 0; kt < 49; kt++) {
        const int kb = k0 + kt * 32;
        {   // stage A: 64m x 32k bf16 -> f32 transposed [k][m]
            const unsigned short* ap = (const unsigned short*)pooled
                + (size_t)(m0 + am) * 12544 + kb + kseg;
            u32x4 raw = *(const u32x4*)ap;
            #pragma unroll
            for (int w = 0; w < 4; w++) {
                unsigned u = raw[w];
                As[kseg + 2 * w    ][am] = __uint_as_float(u << 16);
                As[kseg + 2 * w + 1][am] = __uint_as_float(u & 0xffff0000u);
            }
        }
        {   // stage B: 32k x 128n f32, straight copy
            const u32x4* wp = (const u32x4*)(Wl1 + (size_t)kb * 128);
            u32x4* bp = (u32x4*)Bs;
            #pragma unroll
            for (int e = 0; e < 4; e++) bp[t + 256 * e] = wp[t + 256 * e];
        }
        __syncthreads();
        #pragma unroll
        for (int k = 0; k < 32; k++) {
            f32x4 a  = *(const f32x4*)&As[k][tm * 4];
            f32x4 b0 = *(const f32x4*)&Bs[k][tn * 8];
            f32x4 b1v = *(const f32x4*)&Bs[k][tn * 8 + 4];
            #pragma unroll
            for (int i = 0; i < 4; i++) {
                acc[i][0] += a[i] * b0[0];  acc[i][1] += a[i] * b0[1];
                acc[i][2] += a[i] * b0[2];  acc[i][3] += a[i] * b0[3];
                acc[i][4] += a[i] * b1v[0]; acc[i][5] += a[i] * b1v[1];
                acc[i][6] += a[i] * b1v[2]; acc[i][7] += a[i] * b1v[3];
            }
        }
        __syncthreads();
    }
    float* pp = part + ((size_t)ks * 4096 + m0) * 128;
    #pragma unroll
    for (int i = 0; i < 4; i++)
        #pragma unroll
        for (int j = 0; j < 8; j++)
            pp[(tm * 4 + i) * 128 + tn * 8 + j] = acc[i][j];
}

// ---------------------------------------------------------------------------
// Kernel 3: reduce split-K partials + bias + relu, FC2 (128->10), log_softmax.
// One thread per image.
// ---------------------------------------------------------------------------
__global__ __launch_bounds__(256)
void fc2_lsm(const float* __restrict__ part, const float* __restrict__ bl1,
             const float* __restrict__ Wl2, const float* __restrict__ bl2,
             float* __restrict__ out)
{
    int img = blockIdx.x * 256 + threadIdx.x;   // 4096 threads
    float acc[10];
    #pragma unroll
    for (int c = 0; c < 10; c++) acc[c] = bl2[c];
    const float* pb = part + (size_t)img * 128;
    for (int n = 0; n < 128; n++) {
        float s = bl1[n];
        #pragma unroll
        for (int ksi = 0; ksi < 8; ksi++) s += pb[(size_t)ksi * 4096 * 128 + n];
        float h = s > 0.f ? s : 0.f;
        #pragma unroll
        for (int c = 0; c < 10; c++) acc[c] += h * Wl2[n * 10 + c];
    }
    float mx = acc[0];
    #pragma unroll
    for (int c = 1; c < 10; c++) mx = acc[c] > mx ? acc[c] : mx;
    float se = 0.f;
    #pragma unroll
    for (int c = 0; c < 10; c++) se += expf(acc[c] - mx);
    float lse = logf(se);
    #pragma unroll
    for (int c = 0; c < 10; c++) out[img * 10 + c] = acc[c] - mx - lse;
}

// ---------------------------------------------------------------------------
extern "C" void kernel_launch(void* const* d_in, const int* in_sizes, int n_in,
                              void* d_out, int out_size, void* d_ws, size_t ws_size,
                              hipStream_t stream) {
    const float* x   = (const float*)d_in[0];
    const float* W1  = (const float*)d_in[1];
    const float* b1  = (const float*)d_in[2];
    const float* W2  = (const float*)d_in[3];
    const float* b2  = (const float*)d_in[4];
    const float* Wl1 = (const float*)d_in[5];
    const float* bl1 = (const float*)d_in[6];
    const float* Wl2 = (const float*)d_in[7];
    const float* bl2 = (const float*)d_in[8];
    float* out = (float*)d_out;

    char* ws = (char*)d_ws;
    bf16*  w2g    = (bf16*)ws;                                   // 36,864 B
    bf16*  pooled = (bf16*)(ws + 65536);                         // 102,760,448 B
    float* part   = (float*)(ws + 65536 + 102760448);            // 16,777,216 B

    prep_w2  <<<72,            256, 0, stream>>>(W2, w2g);
    conv_fused<<<16384,        256, 0, stream>>>(x, W1, b1, w2g, b2, pooled);
    fc1      <<<dim3(64, 8),   256, 0, stream>>>(pooled, Wl1, part);
    fc2_lsm  <<<16,            256, 0, stream>>>(part, bl1, Wl2, bl2, out);
}

// Round 2
// 466.387 us; speedup vs baseline: 1.5819x; 1.5819x over previous
//
#include <hip/hip_runtime.h>
#include <math.h>

typedef __bf16 bf16;
typedef __bf16 bf16x8 __attribute__((ext_vector_type(8)));
typedef float f32x4 __attribute__((ext_vector_type(4)));
typedef unsigned int u32x4 __attribute__((ext_vector_type(4)));

__device__ __forceinline__ void load_lds16(const void* g, void* l) {
    __builtin_amdgcn_global_load_lds(
        (const __attribute__((address_space(1))) unsigned int*)g,
        (__attribute__((address_space(3))) unsigned int*)l, 16, 0, 0);
}

// ---------------------------------------------------------------------------
// prep_w2: W2 [cout][ci][tap] f32 -> [tap][cout][ci] bf16, bank-swizzled:
// physical idx = ((tap*64+cout)*32 + ci) ^ ((cout&6)<<2)
// ---------------------------------------------------------------------------
__global__ void prep_w2(const float* __restrict__ W2, bf16* __restrict__ w2g) {
    int e = blockIdx.x * 256 + threadIdx.x;     // logical (tap*64+cout)*32+ci
    int ci   = e & 31;
    int rest = e >> 5;
    int cout = rest & 63;
    int tap  = rest >> 6;
    w2g[e ^ ((cout & 6) << 2)] = (bf16)W2[cout * 288 + ci * 9 + tap];
}

// ---------------------------------------------------------------------------
// prep_wl1t: Wl1 f32 [12544][128] -> bf16 transposed [128][12544]
// ---------------------------------------------------------------------------
__global__ void prep_wl1t(const float* __restrict__ Wl1, bf16* __restrict__ wl1t) {
    int n = blockIdx.y;
    int k = blockIdx.x * 256 + threadIdx.x;
    wl1t[(long)n * 12544 + k] = (bf16)Wl1[(long)k * 128 + n];
}

// ---------------------------------------------------------------------------
// conv_fused: conv1(masked,relu) + conv2(masked,relu,MFMA) + 2x2 maxpool.
// One block = one image * 4 pooled rows. h1s swizzled [pos][ci^] bf16.
// ---------------------------------------------------------------------------
__global__ __launch_bounds__(256, 2)
void conv_fused(const float* __restrict__ x, const float* __restrict__ W1,
                const float* __restrict__ b1, const bf16* __restrict__ w2g,
                const float* __restrict__ b2, bf16* __restrict__ pooled)
{
    __shared__ __attribute__((aligned(16))) bf16  h1s[10 * 30 * 32];
    __shared__ __attribute__((aligned(16))) bf16  w2s[9 * 64 * 32];
    __shared__ __attribute__((aligned(16))) float xs[12 * 32];

    const int t    = threadIdx.x;
    const int lane = t & 63;
    const int wv   = t >> 6;
    const int img  = blockIdx.x >> 2;
    const int rb   = blockIdx.x & 3;
    const int pr0  = rb * 4;

    const float* xi = x + img * 784;

    // early: conv1 weights into regs (hide latency behind staging)
    const int ci = t & 31;
    const int g  = t >> 5;          // 0..7; g<7 active in conv1 (7*4=28 cols)
    float w1r[9];
    #pragma unroll
    for (int k = 0; k < 9; k++) w1r[k] = W1[ci * 9 + k];
    const float b1r = b1[ci];

    // stage x tile: xs[j][c] = x[2*pr0-2+j][c-1]
    for (int e = t; e < 12 * 32; e += 256) {
        int j  = e >> 5;
        int c  = e & 31;
        int xr = 2 * pr0 - 2 + j;
        int xc = c - 1;
        float v = 0.f;
        if (xr >= 0 && xr < 28 && xc >= 0 && xc < 28) v = xi[xr * 28 + xc];
        xs[e] = v;
    }
    // zero h1s (halo must be 0)
    {
        unsigned int* hz = (unsigned int*)h1s;
        for (int e = t; e < 4800; e += 256) hz[e] = 0u;
    }
    __syncthreads();

    // issue async W2 staging (identity copy, pre-swizzled) — overlaps conv1
    {
        const unsigned int* src = (const unsigned int*)w2g;
        unsigned int* dst = (unsigned int*)w2s;
        #pragma unroll
        for (int it = 0; it < 9; it++) {
            int cb = (wv * 9 + it) * 64;            // wave-uniform chunk base
            load_lds16(src + (cb + lane) * 4, dst + cb * 4);
        }
    }

    // ---- conv1: register sliding window, 4-col strip per thread
    if (g < 7) {
        const int c0 = g * 4;
        float win[3][6];
        #pragma unroll
        for (int j0 = 0; j0 < 2; j0++) {
            f32x4 v = *(const f32x4*)&xs[j0 * 32 + c0];
            win[j0][0] = v[0]; win[j0][1] = v[1]; win[j0][2] = v[2]; win[j0][3] = v[3];
            win[j0][4] = xs[j0 * 32 + c0 + 4];
            win[j0][5] = xs[j0 * 32 + c0 + 5];
        }
        #pragma unroll
        for (int r = 0; r < 10; r++) {
            {   // load row r+2 into rotating slot
                float* d = win[(r + 2) % 3];
                f32x4 v = *(const f32x4*)&xs[(r + 2) * 32 + c0];
                d[0] = v[0]; d[1] = v[1]; d[2] = v[2]; d[3] = v[3];
                d[4] = xs[(r + 2) * 32 + c0 + 4];
                d[5] = xs[(r + 2) * 32 + c0 + 5];
            }
            int ghr = 2 * pr0 - 1 + r;
            if (ghr >= 0 && ghr <= 27) {
                const float* a0 = win[r % 3];
                const float* a1 = win[(r + 1) % 3];
                const float* a2 = win[(r + 2) % 3];
                #pragma unroll
                for (int j = 0; j < 4; j++) {
                    float s = b1r
                        + a0[j] * w1r[0] + a0[j + 1] * w1r[1] + a0[j + 2] * w1r[2]
                        + a1[j] * w1r[3] + a1[j + 1] * w1r[4] + a1[j + 2] * w1r[5]
                        + a2[j] * w1r[6] + a2[j + 1] * w1r[7] + a2[j + 2] * w1r[8];
                    float cm = a1[j + 1];                   // active-site mask
                    float o  = (cm != 0.f && s > 0.f) ? s : 0.f;
                    int p = r * 30 + c0 + j + 1;
                    h1s[(p * 32 + ci) ^ ((p & 6) << 2)] = (bf16)o;
                }
            }
        }
    }
    __syncthreads();    // h1s ready; w2s async loads drained

    // ---- conv2 via MFMA 16x16x32 bf16
    const int ml  = lane & 15;
    const int kg  = lane >> 4;
    const int nMt = (rb < 3) ? 14 : 7;

    f32x4 acc[4][4];
    {
        f32x4 z = {0.f, 0.f, 0.f, 0.f};
        #pragma unroll
        for (int i = 0; i < 4; i++)
            #pragma unroll
            for (int j = 0; j < 4; j++) acc[i][j] = z;
    }

    int pbl[4];
    int nMy = 0;
    #pragma unroll
    for (int i = 0; i < 4; i++) {
        int Mt = wv + 4 * i;
        if (Mt < nMt) {
            int m    = Mt * 16 + ml;
            int site = m >> 2;
            int q    = m & 3;
            int pi   = site / 14;
            int pj   = site - pi * 14;
            int y    = 2 * pi + (q >> 1);
            int xx   = 2 * pj + (q & 1);
            pbl[i]   = y * 30 + xx;
            nMy = i + 1;
        }
    }
    int bsw[4];
    #pragma unroll
    for (int nt = 0; nt < 4; nt++) {
        int co = nt * 16 + ml;
        bsw[nt] = (co * 32 + kg * 8) ^ ((co & 6) << 2);
    }

    #pragma unroll
    for (int kt = 0; kt < 9; kt++) {
        const int ky = kt / 3, kx = kt % 3;
        bf16x8 bfr[4];
        #pragma unroll
        for (int nt = 0; nt < 4; nt++)
            bfr[nt] = *(const bf16x8*)&w2s[kt * 2048 + bsw[nt]];
        const int dp = ky * 30 + kx;
        #pragma unroll
        for (int i = 0; i < 4; i++) {
            if (i < nMy) {
                int p = pbl[i] + dp;
                bf16x8 a = *(const bf16x8*)&h1s[(p * 32 + kg * 8) ^ ((p & 6) << 2)];
                #pragma unroll
                for (int nt = 0; nt < 4; nt++)
                    acc[i][nt] = __builtin_amdgcn_mfma_f32_16x16x32_bf16(
                        a, bfr[nt], acc[i][nt], 0, 0, 0);
            }
        }
    }
    __syncthreads();

    // ---- epilogue: +bias, mask, relu, 2x2 maxpool (quad in lane regs)
    bf16* pool_s = h1s;     // overlay: [cout][56 sites] bf16 (unswizzled)
    {
        float bias[4];
        #pragma unroll
        for (int nt = 0; nt < 4; nt++) bias[nt] = b2[nt * 16 + ml];
        #pragma unroll
        for (int i = 0; i < 4; i++) {
            if (i < nMy) {
                int Mt   = wv + 4 * i;
                int site = Mt * 4 + kg;
                int pi   = site / 14;
                int pj   = site - pi * 14;
                #pragma unroll
                for (int nt = 0; nt < 4; nt++) {
                    int cout = nt * 16 + ml;
                    float pmax = 0.f;
                    #pragma unroll
                    for (int r = 0; r < 4; r++) {
                        float v  = acc[i][nt][r] + bias[nt];
                        int y    = 2 * pi + (r >> 1);
                        int xx   = 2 * pj + (r & 1);
                        float cm = xs[(y + 2) * 32 + xx + 1];
                        v = (cm != 0.f && v > 0.f) ? v : 0.f;
                        pmax = v > pmax ? v : pmax;
                    }
                    pool_s[cout * 56 + site] = (bf16)pmax;
                }
            }
        }
    }
    __syncthreads();

    // coalesced write-out (dwords): pooled[img][cout*196 + rb*56 + site]
    {
        const int half = (rb < 3) ? 28 : 14;
        const unsigned int* ps = (const unsigned int*)pool_s;
        unsigned int* op = (unsigned int*)pooled;
        const int total = 64 * half;
        for (int e = t; e < total; e += 256) {
            int cout = e / half;
            int wd   = e - cout * half;
            op[img * 6272 + cout * 98 + rb * 28 + wd] = ps[cout * 28 + wd];
        }
    }
}

// ---------------------------------------------------------------------------
// fc1: bf16 MFMA split-K GEMM. part[ks][m][n] = A[m, ks*1568:+1568] * Wl1
// A = pooled bf16 [4096][12544]; B = wl1t bf16 [128][12544] (n-major).
// grid (64 Mb, 8 Ks), block 256 = 4 waves in 2x2 (wave: 32M x 64N).
// ---------------------------------------------------------------------------
__global__ __launch_bounds__(256, 4)
void fc1(const bf16* __restrict__ pooled, const bf16* __restrict__ wl1t,
         float* __restrict__ part)
{
    __shared__ __attribute__((aligned(16))) bf16 As[64 * 32];    // swizzled
    __shared__ __attribute__((aligned(16))) bf16 Bs[128 * 32];   // swizzled

    const int t    = threadIdx.x;
    const int lane = t & 63;
    const int wv   = t >> 6;
    const int ml   = lane & 15;
    const int kg   = lane >> 4;
    const int wm   = wv & 1;
    const int wn   = wv >> 1;
    const int m0   = blockIdx.x * 64;
    const int ks   = blockIdx.y;
    const int k0   = ks * 1568;

    // A staging: 1 chunk/thread. chunk t -> img t>>2, k-slot t&3 (swizzled src)
    const int aimg = t >> 2;
    const int aswz = (t & 3) ^ ((aimg >> 1) & 3);
    const bf16* asrc = pooled + (long)(m0 + aimg) * 12544 + aswz * 8;
    bf16* adst = As + wv * 512;                       // wave-uniform

    // B staging: 2 chunks/thread (n and n+64 share swizzle since 64&6==0... (n+64)>>1 diff 32, &3 same)
    const int bn   = t >> 2;
    const int bswz = (t & 3) ^ ((bn >> 1) & 3);
    const bf16* bsrc0 = wl1t + (long)bn * 12544 + bswz * 8;
    const bf16* bsrc1 = wl1t + (long)(bn + 64) * 12544 + bswz * 8;
    bf16* bdst0 = Bs + wv * 512;
    bf16* bdst1 = Bs + 2048 + wv * 512;

    // fragment read addresses (constant across kt)
    const bf16* apf[2];
    #pragma unroll
    for (int i = 0; i < 2; i++) {
        int m = wm * 32 + i * 16 + ml;
        apf[i] = &As[(m * 32 + kg * 8) ^ ((m & 6) << 2)];
    }
    const bf16* bpf[4];
    #pragma unroll
    for (int j = 0; j < 4; j++) {
        int n = wn * 64 + j * 16 + ml;
        bpf[j] = &Bs[(n * 32 + kg * 8) ^ ((n & 6) << 2)];
    }

    f32x4 acc[2][4];
    {
        f32x4 z = {0.f, 0.f, 0.f, 0.f};
        #pragma unroll
        for (int i = 0; i < 2; i++)
            #pragma unroll
            for (int j = 0; j < 4; j++) acc[i][j] = z;
    }

    for (int kt = 0; kt < 49; kt++) {
        const int kb = k0 + kt * 32;
        __syncthreads();                    // prev tile consumed
        load_lds16(asrc + kb, adst);
        load_lds16(bsrc0 + kb, bdst0);
        load_lds16(bsrc1 + kb, bdst1);
        __syncthreads();                    // staging complete
        bf16x8 af[2], bf[4];
        #pragma unroll
        for (int i = 0; i < 2; i++) af[i] = *(const bf16x8*)apf[i];
        #pragma unroll
        for (int j = 0; j < 4; j++) bf[j] = *(const bf16x8*)bpf[j];
        #pragma unroll
        for (int i = 0; i < 2; i++)
            #pragma unroll
            for (int j = 0; j < 4; j++)
                acc[i][j] = __builtin_amdgcn_mfma_f32_16x16x32_bf16(
                    af[i], bf[j], acc[i][j], 0, 0, 0);
    }

    float* pp = part + ((long)ks * 4096 + m0 + wm * 32) * 128 + wn * 64;
    #pragma unroll
    for (int i = 0; i < 2; i++)
        #pragma unroll
        for (int j = 0; j < 4; j++)
            #pragma unroll
            for (int r = 0; r < 4; r++)
                pp[(i * 16 + kg * 4 + r) * 128 + j * 16 + ml] = acc[i][j][r];
}

// ---------------------------------------------------------------------------
// fc2_lsm: one wave per image. lane covers n and n+64; shuffle-reduce logits.
// ---------------------------------------------------------------------------
__global__ __launch_bounds__(256)
void fc2_lsm(const float* __restrict__ part, const float* __restrict__ bl1,
             const float* __restrict__ Wl2, const float* __restrict__ bl2,
             float* __restrict__ out)
{
    const int wv   = threadIdx.x >> 6;
    const int lane = threadIdx.x & 63;
    const int img  = blockIdx.x * 4 + wv;
    const float* pb = part + (long)img * 128;

    float ac[10];
    #pragma unroll
    for (int c = 0; c < 10; c++) ac[c] = 0.f;

    #pragma unroll
    for (int u = 0; u < 2; u++) {
        int n = lane + 64 * u;
        float s = bl1[n];
        #pragma unroll
        for (int k = 0; k < 8; k++) s += pb[(long)k * 4096 * 128 + n];
        float h = s > 0.f ? s : 0.f;
        #pragma unroll
        for (int c = 0; c < 10; c++) ac[c] += h * Wl2[n * 10 + c];
    }
    #pragma unroll
    for (int o = 32; o > 0; o >>= 1)
        #pragma unroll
        for (int c = 0; c < 10; c++) ac[c] += __shfl_down(ac[c], o, 64);

    if (lane == 0) {
        float lg[10], mx = -1e30f;
        #pragma unroll
        for (int c = 0; c < 10; c++) {
            lg[c] = ac[c] + bl2[c];
            mx = lg[c] > mx ? lg[c] : mx;
        }
        float se = 0.f;
        #pragma unroll
        for (int c = 0; c < 10; c++) se += __expf(lg[c] - mx);
        float ls = __logf(se);
        #pragma unroll
        for (int c = 0; c < 10; c++) out[img * 10 + c] = lg[c] - mx - ls;
    }
}

// ---------------------------------------------------------------------------
extern "C" void kernel_launch(void* const* d_in, const int* in_sizes, int n_in,
                              void* d_out, int out_size, void* d_ws, size_t ws_size,
                              hipStream_t stream) {
    const float* x   = (const float*)d_in[0];
    const float* W1  = (const float*)d_in[1];
    const float* b1  = (const float*)d_in[2];
    const float* W2  = (const float*)d_in[3];
    const float* b2  = (const float*)d_in[4];
    const float* Wl1 = (const float*)d_in[5];
    const float* bl1 = (const float*)d_in[6];
    const float* Wl2 = (const float*)d_in[7];
    const float* bl2 = (const float*)d_in[8];
    float* out = (float*)d_out;

    char* ws = (char*)d_ws;
    bf16*  w2g    = (bf16*)ws;                                   // 36,864 B
    bf16*  wl1t   = (bf16*)(ws + 65536);                         // 3,211,264 B
    bf16*  pooled = (bf16*)(ws + 65536 + 4194304);               // 102,760,448 B
    float* part   = (float*)(ws + 65536 + 4194304 + 102760448);  // 16,777,216 B

    prep_w2   <<<72,             256, 0, stream>>>(W2, w2g);
    prep_wl1t <<<dim3(49, 128),  256, 0, stream>>>(Wl1, wl1t);
    conv_fused<<<16384,          256, 0, stream>>>(x, W1, b1, w2g, b2, pooled);
    fc1       <<<dim3(64, 8),    256, 0, stream>>>(pooled, wl1t, part);
    fc2_lsm   <<<1024,           256, 0, stream>>>(part, bl1, Wl2, bl2, out);
}